// Round 11
// baseline (81.378 us; speedup 1.0000x reference)
//
#include <hip/hip_runtime.h>
#include <hip/hip_bf16.h>

#define B_ 32
#define T_ 256
#define NIN_ 128
#define H_ 32
#define NOUT_ 128
#define R_ (B_ * T_)   // 8192 rows

#define C2L2E 2.88539008177792681472f   // 2*log2(e)
#define L2E   1.44269504088896341f
#define LN2   0.69314718055994531f

__device__ __forceinline__ float rfl(float x) {
    return __uint_as_float(__builtin_amdgcn_readfirstlane(__float_as_uint(x)));
}

// ---------------------------------------------------------------------------
// Kernel 1 (fused): per block = 8 rows x 32 h (256 threads).
// x rows staged cooperatively in LDS (one float4 load/thread).
//   y = x @ W_in^T + b_in ; Eh = exp2(c*y@W_h^T) ; Eo = exp2(c*y@W_o^T)
// ---------------------------------------------------------------------------
__global__ void __launch_bounds__(256) k_yho(
        const float* __restrict__ x,
        const float* __restrict__ W_in,
        const float* __restrict__ b_in,
        const float* __restrict__ W_h,
        const float* __restrict__ W_o,
        float* __restrict__ y,
        float* __restrict__ Eh,
        float* __restrict__ Eo) {
    __shared__ float xs[8][NIN_];   // 4 KB
    __shared__ float ys[8][H_];     // 1 KB
    const int t   = threadIdx.x;
    const int r   = t >> 5;              // local row 0..7
    const int hh  = t & 31;
    const int row = blockIdx.x * 8 + r;
    const int idx = row * H_ + hh;

    reinterpret_cast<float4*>(&xs[0][0])[t] =
        reinterpret_cast<const float4*>(x + (blockIdx.x * 8) * NIN_)[t];
    __syncthreads();

    {
        const float4* xl = reinterpret_cast<const float4*>(&xs[r][0]);
        const float4* w4 = reinterpret_cast<const float4*>(W_in + hh * NIN_);
        float a0 = b_in[hh], a1 = 0.f;
        #pragma unroll
        for (int k = 0; k < NIN_ / 8; ++k) {
            float4 xv0 = xl[2 * k],     wv0 = w4[2 * k];
            float4 xv1 = xl[2 * k + 1], wv1 = w4[2 * k + 1];
            a0 += xv0.x * wv0.x + xv0.y * wv0.y + xv0.z * wv0.z + xv0.w * wv0.w;
            a1 += xv1.x * wv1.x + xv1.y * wv1.y + xv1.z * wv1.z + xv1.w * wv1.w;
        }
        float acc = a0 + a1;
        ys[r][hh] = acc;
        y[idx] = acc;
    }
    __syncthreads();

    {
        const float4* y4  = reinterpret_cast<const float4*>(&ys[r][0]);
        const float4* wh4 = reinterpret_cast<const float4*>(W_h + hh * H_);
        const float4* wo4 = reinterpret_cast<const float4*>(W_o + hh * H_);
        float ah0 = 0.f, ah1 = 0.f, ao0 = 0.f, ao1 = 0.f;
        #pragma unroll
        for (int k = 0; k < H_ / 8; ++k) {
            float4 yv0 = y4[2 * k],     hv0 = wh4[2 * k],     ov0 = wo4[2 * k];
            float4 yv1 = y4[2 * k + 1], hv1 = wh4[2 * k + 1], ov1 = wo4[2 * k + 1];
            ah0 += yv0.x * hv0.x + yv0.y * hv0.y + yv0.z * hv0.z + yv0.w * hv0.w;
            ah1 += yv1.x * hv1.x + yv1.y * hv1.y + yv1.z * hv1.z + yv1.w * hv1.w;
            ao0 += yv0.x * ov0.x + yv0.y * ov0.y + yv0.z * ov0.z + yv0.w * ov0.w;
            ao1 += yv1.x * ov1.x + yv1.y * ov1.y + yv1.z * ov1.z + yv1.w * ov1.w;
        }
        Eh[idx] = __builtin_amdgcn_exp2f((ah0 + ah1) * C2L2E);
        Eo[idx] = __builtin_amdgcn_exp2f((ao0 + ao1) * C2L2E);
    }
}

// ---------------------------------------------------------------------------
// Kernel 2: ONE QUERY PER WAVE (max wave-parallelism: 8192 waves = 32/CU).
// No Eo LDS tile (32KB tile is L1-resident; staging it cost occupancy).
// eh[32], w2[32] -> SGPR via readfirstlane; VGPR kept ~56 so 8 waves/SIMD fit.
// 256-thread blocks (4 waves = 4 queries), LDS only att_t+ctx (4.6KB).
// ---------------------------------------------------------------------------
__global__ void __launch_bounds__(256) k_att(
        const float* __restrict__ y,
        const float* __restrict__ Eh,
        const float* __restrict__ Eo,
        const float* __restrict__ V,
        const float* __restrict__ W_out,
        const float* __restrict__ b_out,
        float* __restrict__ out) {
    __shared__ float att_t[4][T_];       // 4 KB, transposed index
    __shared__ float ctx_lds[4][H_];     // 512 B

    const int t    = threadIdx.x;
    const int w    = __builtin_amdgcn_readfirstlane(t >> 6);  // wave 0..3
    const int lane = t & 63;
    const int r    = blockIdx.x * 4 + w;      // query row
    const int bb   = r >> 8;                  // batch

    // ---- preamble: eh -> SGPR, w2 -> SGPR, vsum -> SGPR ----
    float eh[H_];    // rfl'd -> SGPR
    float w2[H_];    // rfl'd -> SGPR
    float vsum = 0.f;
    {
        const float4* h4 = reinterpret_cast<const float4*>(Eh + r * H_);
        const float4* V4 = reinterpret_cast<const float4*>(V);
        #pragma unroll
        for (int p = 0; p < 8; ++p) {
            float4 a = h4[p], v = V4[p];
            eh[4 * p + 0] = rfl(a.x); eh[4 * p + 1] = rfl(a.y);
            eh[4 * p + 2] = rfl(a.z); eh[4 * p + 3] = rfl(a.w);
            w2[4 * p + 0] = rfl(v.x * -2.0f); w2[4 * p + 1] = rfl(v.y * -2.0f);
            w2[4 * p + 2] = rfl(v.z * -2.0f); w2[4 * p + 3] = rfl(v.w * -2.0f);
            vsum += v.x + v.y + v.z + v.w;
        }
        vsum = rfl(vsum);
    }

    // ---- e for 4 j's per lane; Eo rows straight from L1/L2 ----
    const float* obase = Eo + (bb * T_) * H_;
    float E[4];
    #pragma unroll
    for (int q = 0; q < 4; ++q) {
        const int j = lane + 64 * q;
        const float4* o4 = reinterpret_cast<const float4*>(obase + j * H_);
        float4 ev[8];
        #pragma unroll
        for (int p = 0; p < 8; ++p) ev[p] = o4[p];
        float a0 = 0.f, a1 = 0.f, a2 = 0.f, a3 = 0.f;
        #pragma unroll
        for (int p = 0; p < 8; ++p) {
            const int k = 4 * p;
            float d;
            d  = fmaf(eh[k + 0], ev[p].x, 1.0f);
            a0 = fmaf(w2[k + 0], __builtin_amdgcn_rcpf(d), a0);
            d  = fmaf(eh[k + 1], ev[p].y, 1.0f);
            a1 = fmaf(w2[k + 1], __builtin_amdgcn_rcpf(d), a1);
            d  = fmaf(eh[k + 2], ev[p].z, 1.0f);
            a2 = fmaf(w2[k + 2], __builtin_amdgcn_rcpf(d), a2);
            d  = fmaf(eh[k + 3], ev[p].w, 1.0f);
            a3 = fmaf(w2[k + 3], __builtin_amdgcn_rcpf(d), a3);
        }
        E[q] = ((a0 + a1) + (a2 + a3)) + vsum;
    }

    // ---- wave-local softmax ----
    float m = fmaxf(fmaxf(E[0], E[1]), fmaxf(E[2], E[3]));
    #pragma unroll
    for (int off = 1; off < 64; off <<= 1)
        m = fmaxf(m, __shfl_xor(m, off));
    float s = 0.f;
    #pragma unroll
    for (int q = 0; q < 4; ++q)
        s += __builtin_amdgcn_exp2f((E[q] - m) * L2E);
    #pragma unroll
    for (int off = 1; off < 64; off <<= 1)
        s += __shfl_xor(s, off);
    const float lse = m + __builtin_amdgcn_logf(s) * LN2;

    // transposed store: att_t[w][ (j&31)*8 + (j>>5) ]
    #pragma unroll
    for (int q = 0; q < 4; ++q) {
        const int j = lane + 64 * q;
        att_t[w][(j & 31) * 8 + (j >> 5)] = E[q] - lse;
    }
    // same-wave LDS produce->consume: ordered by lgkmcnt, no barrier needed

    // ---- context: lane = (channel-group hg 0..7) x (jslice js 0..7) ----
    {
        const int hg = lane & 7;
        const int js = lane >> 3;
        const float4* yb = reinterpret_cast<const float4*>(
            y + bb * T_ * H_ + (js * 32) * H_ + hg * 4);
        float4 c = {0, 0, 0, 0};
        #pragma unroll
        for (int n = 0; n < 32; ++n) {
            float4 yv = yb[n * (H_ / 4)];          // imm offset n*128B
            float a = att_t[w][n * 8 + js];
            c.x = fmaf(a, yv.x, c.x); c.y = fmaf(a, yv.y, c.y);
            c.z = fmaf(a, yv.z, c.z); c.w = fmaf(a, yv.w, c.w);
        }
        #pragma unroll
        for (int off = 8; off < 64; off <<= 1) {
            c.x += __shfl_xor(c.x, off); c.y += __shfl_xor(c.y, off);
            c.z += __shfl_xor(c.z, off); c.w += __shfl_xor(c.w, off);
        }
        if (js == 0)
            *reinterpret_cast<float4*>(&ctx_lds[w][4 * hg]) = c;
    }

    // ---- output projection: 2 channels per lane ----
    float4 cv[8];
    #pragma unroll
    for (int p = 0; p < 8; ++p)
        cv[p] = *reinterpret_cast<const float4*>(&ctx_lds[w][4 * p]);
    #pragma unroll
    for (int ho = 0; ho < 2; ++ho) {
        const int oc = lane + 64 * ho;
        const float4* w4 = reinterpret_cast<const float4*>(W_out + oc * H_);
        float b0 = b_out[oc], p1 = 0.f, p2 = 0.f, p3 = 0.f;
        #pragma unroll
        for (int p = 0; p < 8; p += 4) {
            float4 wv0 = w4[p + 0], wv1 = w4[p + 1], wv2 = w4[p + 2], wv3 = w4[p + 3];
            b0 += wv0.x * cv[p + 0].x + wv0.y * cv[p + 0].y + wv0.z * cv[p + 0].z + wv0.w * cv[p + 0].w;
            p1 += wv1.x * cv[p + 1].x + wv1.y * cv[p + 1].y + wv1.z * cv[p + 1].z + wv1.w * cv[p + 1].w;
            p2 += wv2.x * cv[p + 2].x + wv2.y * cv[p + 2].y + wv2.z * cv[p + 2].z + wv2.w * cv[p + 2].w;
            p3 += wv3.x * cv[p + 3].x + wv3.y * cv[p + 3].y + wv3.z * cv[p + 3].z + wv3.w * cv[p + 3].w;
        }
        out[r * NOUT_ + oc] = (b0 + p1) + (p2 + p3);
    }
}

// ---------------------------------------------------------------------------
extern "C" void kernel_launch(void* const* d_in, const int* in_sizes, int n_in,
                              void* d_out, int out_size, void* d_ws, size_t ws_size,
                              hipStream_t stream) {
    const float* x     = (const float*)d_in[0];
    const float* W_in  = (const float*)d_in[1];
    const float* b_in  = (const float*)d_in[2];
    const float* W_h   = (const float*)d_in[3];
    const float* W_o   = (const float*)d_in[4];
    const float* V     = (const float*)d_in[5];
    const float* W_out = (const float*)d_in[6];
    const float* b_out = (const float*)d_in[7];
    float* out = (float*)d_out;

    // workspace layout: y | Eh | Eo  (each R_*H_ floats = 1 MB)
    float* y  = (float*)d_ws;
    float* Eh = y + R_ * H_;
    float* Eo = Eh + R_ * H_;

    k_yho<<<R_ / 8, 256, 0, stream>>>(x, W_in, b_in, W_h, W_o, y, Eh, Eo);
    k_att<<<R_ / 4, 256, 0, stream>>>(y, Eh, Eo, V, W_out, b_out, out);
}

// Round 12
// 56.571 us; speedup vs baseline: 1.4385x; 1.4385x over previous
//
#include <hip/hip_runtime.h>
#include <hip/hip_bf16.h>

#define B_ 32
#define T_ 256
#define NIN_ 128
#define H_ 32
#define NOUT_ 128
#define R_ (B_ * T_)   // 8192 rows

#define C2L2E 2.88539008177792681472f   // 2*log2(e)
#define L2E   1.44269504088896341f
#define LN2   0.69314718055994531f

__device__ __forceinline__ float rcpf(float x) { return __builtin_amdgcn_rcpf(x); }

// ---------------------------------------------------------------------------
// Kernel 1 (fused): per block = 8 rows x 32 h (256 threads).
// x rows staged cooperatively in LDS (one float4 load/thread).
//   y = x @ W_in^T + b_in ; Eh = exp2(c*y@W_h^T) ; Eo = exp2(c*y@W_o^T)
// ---------------------------------------------------------------------------
__global__ void __launch_bounds__(256) k_yho(
        const float* __restrict__ x,
        const float* __restrict__ W_in,
        const float* __restrict__ b_in,
        const float* __restrict__ W_h,
        const float* __restrict__ W_o,
        float* __restrict__ y,
        float* __restrict__ Eh,
        float* __restrict__ Eo) {
    __shared__ float xs[8][NIN_];   // 4 KB
    __shared__ float ys[8][H_];     // 1 KB
    const int t   = threadIdx.x;
    const int r   = t >> 5;              // local row 0..7
    const int hh  = t & 31;
    const int row = blockIdx.x * 8 + r;
    const int idx = row * H_ + hh;

    reinterpret_cast<float4*>(&xs[0][0])[t] =
        reinterpret_cast<const float4*>(x + (blockIdx.x * 8) * NIN_)[t];
    __syncthreads();

    {
        const float4* xl = reinterpret_cast<const float4*>(&xs[r][0]);
        const float4* w4 = reinterpret_cast<const float4*>(W_in + hh * NIN_);
        float a0 = b_in[hh], a1 = 0.f;
        #pragma unroll
        for (int k = 0; k < NIN_ / 8; ++k) {
            float4 xv0 = xl[2 * k],     wv0 = w4[2 * k];
            float4 xv1 = xl[2 * k + 1], wv1 = w4[2 * k + 1];
            a0 += xv0.x * wv0.x + xv0.y * wv0.y + xv0.z * wv0.z + xv0.w * wv0.w;
            a1 += xv1.x * wv1.x + xv1.y * wv1.y + xv1.z * wv1.z + xv1.w * wv1.w;
        }
        float acc = a0 + a1;
        ys[r][hh] = acc;
        y[idx] = acc;
    }
    __syncthreads();

    {
        const float4* y4  = reinterpret_cast<const float4*>(&ys[r][0]);
        const float4* wh4 = reinterpret_cast<const float4*>(W_h + hh * H_);
        const float4* wo4 = reinterpret_cast<const float4*>(W_o + hh * H_);
        float ah0 = 0.f, ah1 = 0.f, ao0 = 0.f, ao1 = 0.f;
        #pragma unroll
        for (int k = 0; k < H_ / 8; ++k) {
            float4 yv0 = y4[2 * k],     hv0 = wh4[2 * k],     ov0 = wo4[2 * k];
            float4 yv1 = y4[2 * k + 1], hv1 = wh4[2 * k + 1], ov1 = wo4[2 * k + 1];
            ah0 += yv0.x * hv0.x + yv0.y * hv0.y + yv0.z * hv0.z + yv0.w * hv0.w;
            ah1 += yv1.x * hv1.x + yv1.y * hv1.y + yv1.z * hv1.z + yv1.w * hv1.w;
            ao0 += yv0.x * ov0.x + yv0.y * ov0.y + yv0.z * ov0.z + yv0.w * ov0.w;
            ao1 += yv1.x * ov1.x + yv1.y * ov1.y + yv1.z * ov1.z + yv1.w * ov1.w;
        }
        Eh[idx] = __builtin_amdgcn_exp2f((ah0 + ah1) * C2L2E);
        Eo[idx] = __builtin_amdgcn_exp2f((ao0 + ao1) * C2L2E);
    }
}

// ---------------------------------------------------------------------------
// Kernel 2 (flash-style): block = 256 thd = 4 waves; block owns 16 queries.
// lane = (q = lane&15, kq = lane>>4); wave w = j-slice [64w, 64w+64).
// Uses log-softmax LINEARITY: ctx = Sum_j E*y  -  lse * Sum_j y  (no att
// matrix, no rescale; |E|<=vabs so fixed-shift exp, no running max).
// Eo,y tiles staged ONCE per block in LDS; inner loop reads are 4-address
// 16-lane broadcasts (conflict-free); zero global loads in the j-loop.
// Grid 512 = 2 blocks/CU (LDS 76KB), VGPR-rich (2 waves/SIMD) -> deep unroll.
// ---------------------------------------------------------------------------
__global__ void __launch_bounds__(256) k_att(
        const float* __restrict__ y,
        const float* __restrict__ Eh,
        const float* __restrict__ Eo,
        const float* __restrict__ V,
        const float* __restrict__ W_out,
        const float* __restrict__ b_out,
        float* __restrict__ out) {
    __shared__ float eo_s[T_ * H_];        // 32 KB  [j][k]
    __shared__ float y_s[T_ * H_];         // 32 KB  [j][h]
    __shared__ float ctxred[4][16][H_];    // 8 KB   per-wave S1 partials
    __shared__ float sred[4][16];          // 256 B  per-wave s partials
    __shared__ float yps[8][H_];           // 1 KB   ysum partials
    __shared__ float ctxf[16][H_];         // 2 KB   final context

    const int t    = threadIdx.x;
    const int w    = __builtin_amdgcn_readfirstlane(t >> 6);  // wave/j-slice
    const int lane = t & 63;
    const int q    = lane & 15;      // query within block
    const int kq   = lane >> 4;      // k-quarter 0..3
    const int ko   = kq * 8;         // float offset of this lane's k/h slice
    const int bb   = blockIdx.x >> 4;            // batch
    const int qb   = (blockIdx.x & 15) << 4;     // query base within batch
    const int rq   = bb * T_ + qb + q;           // this lane's global query row

    // ---- stage Eo and y tiles (linear layout; staging is 2-way-free) ----
    {
        const float4* eg = reinterpret_cast<const float4*>(Eo + bb * T_ * H_);
        const float4* yg = reinterpret_cast<const float4*>(y  + bb * T_ * H_);
        float4* es = reinterpret_cast<float4*>(eo_s);
        float4* ys = reinterpret_cast<float4*>(y_s);
        #pragma unroll
        for (int n = 0; n < 8; ++n) {
            es[n * 256 + t] = eg[n * 256 + t];
            ys[n * 256 + t] = yg[n * 256 + t];
        }
    }
    __syncthreads();

    // ---- ysum partials: thread (js = t>>5, h = t&31) sums 32 j's ----
    {
        const int h = t & 31, js = t >> 5;
        float p = 0.f;
        #pragma unroll
        for (int n = 0; n < 32; ++n) p += y_s[(js * 32 + n) * H_ + h];
        yps[js][h] = p;
    }

    // ---- preamble: per-lane Eh slice, w2 slice; vsum/vabs via butterfly ----
    float eh8[8], w2v[8];
    float vs, va;
    {
        const float4* ehp = reinterpret_cast<const float4*>(Eh + rq * H_ + ko);
        float4 a = ehp[0], b = ehp[1];
        eh8[0] = a.x; eh8[1] = a.y; eh8[2] = a.z; eh8[3] = a.w;
        eh8[4] = b.x; eh8[5] = b.y; eh8[6] = b.z; eh8[7] = b.w;
        const float4* vp = reinterpret_cast<const float4*>(V + ko);
        float4 v0 = vp[0], v1 = vp[1];
        w2v[0] = v0.x * -2.f; w2v[1] = v0.y * -2.f;
        w2v[2] = v0.z * -2.f; w2v[3] = v0.w * -2.f;
        w2v[4] = v1.x * -2.f; w2v[5] = v1.y * -2.f;
        w2v[6] = v1.z * -2.f; w2v[7] = v1.w * -2.f;
        float pvs = 0.f, pva = 0.f;
        #pragma unroll
        for (int i = 0; i < 8; ++i) {
            pvs += w2v[i] * -0.5f;
            pva += fabsf(w2v[i]) * 0.5f;
        }
        pvs += __shfl_xor(pvs, 16); pvs += __shfl_xor(pvs, 32);
        pva += __shfl_xor(pva, 16); pva += __shfl_xor(pva, 32);
        vs = pvs; va = pva;
    }
    const float soff = -va * L2E;

    // ---- fused score + S1 + s over this wave's 64 j's (all LDS) ----
    float s0 = 0.f, s1 = 0.f;
    float ctx8[8] = {0.f, 0.f, 0.f, 0.f, 0.f, 0.f, 0.f, 0.f};
    #pragma unroll 4
    for (int n = 0; n < 64; ++n) {
        const int jb = ((w << 6) + n) * H_ + ko;
        float4 e0  = *reinterpret_cast<const float4*>(eo_s + jb);
        float4 e1  = *reinterpret_cast<const float4*>(eo_s + jb + 4);
        float4 yv0 = *reinterpret_cast<const float4*>(y_s + jb);
        float4 yv1 = *reinterpret_cast<const float4*>(y_s + jb + 4);
        float a0, a1;
        a0 = w2v[0] * rcpf(fmaf(eh8[0], e0.x, 1.f));
        a1 = w2v[1] * rcpf(fmaf(eh8[1], e0.y, 1.f));
        a0 = fmaf(w2v[2], rcpf(fmaf(eh8[2], e0.z, 1.f)), a0);
        a1 = fmaf(w2v[3], rcpf(fmaf(eh8[3], e0.w, 1.f)), a1);
        a0 = fmaf(w2v[4], rcpf(fmaf(eh8[4], e1.x, 1.f)), a0);
        a1 = fmaf(w2v[5], rcpf(fmaf(eh8[5], e1.y, 1.f)), a1);
        a0 = fmaf(w2v[6], rcpf(fmaf(eh8[6], e1.z, 1.f)), a0);
        a1 = fmaf(w2v[7], rcpf(fmaf(eh8[7], e1.w, 1.f)), a1);
        float E = a0 + a1;
        E += __shfl_xor(E, 16);      // combine 4 k-quarters (bits 4,5)
        E += __shfl_xor(E, 32);
        E += vs;
        float ex = __builtin_amdgcn_exp2f(fmaf(E, L2E, soff));
        if (n & 1) s1 += ex; else s0 += ex;
        ctx8[0] = fmaf(E, yv0.x, ctx8[0]);
        ctx8[1] = fmaf(E, yv0.y, ctx8[1]);
        ctx8[2] = fmaf(E, yv0.z, ctx8[2]);
        ctx8[3] = fmaf(E, yv0.w, ctx8[3]);
        ctx8[4] = fmaf(E, yv1.x, ctx8[4]);
        ctx8[5] = fmaf(E, yv1.y, ctx8[5]);
        ctx8[6] = fmaf(E, yv1.z, ctx8[6]);
        ctx8[7] = fmaf(E, yv1.w, ctx8[7]);
    }

    // ---- write per-wave partials ----
    if (kq == 0) sred[w][q] = s0 + s1;
    {
        float4* cr = reinterpret_cast<float4*>(&ctxred[w][q][ko]);
        float4 c0; c0.x = ctx8[0]; c0.y = ctx8[1]; c0.z = ctx8[2]; c0.w = ctx8[3];
        float4 c1; c1.x = ctx8[4]; c1.y = ctx8[5]; c1.z = ctx8[6]; c1.w = ctx8[7];
        cr[0] = c0; cr[1] = c1;
    }
    __syncthreads();

    // ---- merge: ctxf[q][h] = Sum_w S1 - lse[q] * ysum[h] ----
    #pragma unroll
    for (int rep = 0; rep < 2; ++rep) {
        const int id = t + rep * 256;       // 0..511 -> (q,h)
        const int mq = id >> 5, mh = id & 31;
        float st = (sred[0][mq] + sred[1][mq]) + (sred[2][mq] + sred[3][mq]);
        float lse = va + __builtin_amdgcn_logf(st) * LN2;
        float c = (ctxred[0][mq][mh] + ctxred[1][mq][mh])
                + (ctxred[2][mq][mh] + ctxred[3][mq][mh]);
        float ys2 = ((yps[0][mh] + yps[1][mh]) + (yps[2][mh] + yps[3][mh]))
                  + ((yps[4][mh] + yps[5][mh]) + (yps[6][mh] + yps[7][mh]));
        ctxf[mq][mh] = c - lse * ys2;
    }
    __syncthreads();

    // ---- output projection: thread = (q = t>>4, 8 oc starting (t&15)*8) ----
    {
        const int oq  = t >> 4;
        const int ocb = (t & 15) * 8;
        float4 cv[8];
        #pragma unroll
        for (int p = 0; p < 8; ++p)
            cv[p] = *reinterpret_cast<const float4*>(&ctxf[oq][4 * p]);
        float res[8];
        #pragma unroll
        for (int oo = 0; oo < 8; ++oo) {
            const int oc = ocb + oo;
            const float4* wp = reinterpret_cast<const float4*>(W_out + oc * H_);
            float p0 = b_out[oc], p1 = 0.f, p2 = 0.f, p3 = 0.f;
            #pragma unroll
            for (int p = 0; p < 8; p += 4) {
                float4 w0 = wp[p], w1 = wp[p + 1], w2 = wp[p + 2], w3 = wp[p + 3];
                p0 += w0.x * cv[p].x + w0.y * cv[p].y + w0.z * cv[p].z + w0.w * cv[p].w;
                p1 += w1.x * cv[p+1].x + w1.y * cv[p+1].y + w1.z * cv[p+1].z + w1.w * cv[p+1].w;
                p2 += w2.x * cv[p+2].x + w2.y * cv[p+2].y + w2.z * cv[p+2].z + w2.w * cv[p+2].w;
                p3 += w3.x * cv[p+3].x + w3.y * cv[p+3].y + w3.z * cv[p+3].z + w3.w * cv[p+3].w;
            }
            res[oo] = (p0 + p1) + (p2 + p3);
        }
        float* orow = out + (bb * T_ + qb + oq) * NOUT_ + ocb;
        float4 r0; r0.x = res[0]; r0.y = res[1]; r0.z = res[2]; r0.w = res[3];
        float4 r1; r1.x = res[4]; r1.y = res[5]; r1.z = res[6]; r1.w = res[7];
        *reinterpret_cast<float4*>(orow)     = r0;
        *reinterpret_cast<float4*>(orow + 4) = r1;
    }
}

// ---------------------------------------------------------------------------
extern "C" void kernel_launch(void* const* d_in, const int* in_sizes, int n_in,
                              void* d_out, int out_size, void* d_ws, size_t ws_size,
                              hipStream_t stream) {
    const float* x     = (const float*)d_in[0];
    const float* W_in  = (const float*)d_in[1];
    const float* b_in  = (const float*)d_in[2];
    const float* W_h   = (const float*)d_in[3];
    const float* W_o   = (const float*)d_in[4];
    const float* V     = (const float*)d_in[5];
    const float* W_out = (const float*)d_in[6];
    const float* b_out = (const float*)d_in[7];
    float* out = (float*)d_out;

    // workspace layout: y | Eh | Eo  (each R_*H_ floats = 1 MB)
    float* y  = (float*)d_ws;
    float* Eh = y + R_ * H_;
    float* Eo = Eh + R_ * H_;

    k_yho<<<R_ / 8, 256, 0, stream>>>(x, W_in, b_in, W_h, W_o, y, Eh, Eo);
    k_att<<<R_ / 16, 256, 0, stream>>>(y, Eh, Eo, V, W_out, b_out, out);
}